// Round 8
// baseline (37.310 us; speedup 1.0000x reference)
//
#include <hip/hip_runtime.h>
#include <hip/hip_bf16.h>

#define NN 2048
#define KD 512
#define ODIM 512
#define NHEAD 8
#define HD 64
#define NEG 0.2f

typedef float f32x4 __attribute__((ext_vector_type(4)));
typedef short bf16x8 __attribute__((ext_vector_type(8)));
typedef short bf16x4 __attribute__((ext_vector_type(4)));
typedef unsigned long long u64;
typedef unsigned int u32;

__device__ __forceinline__ short tob(float f) {
  __hip_bfloat16 h = __float2bfloat16(f);
  return *reinterpret_cast<short*>(&h);
}

// async global -> LDS; LDS dest = uniform base + lane*width
__device__ __forceinline__ void gl_lds16(const void* g, void* l) {
  __builtin_amdgcn_global_load_lds(
      (const __attribute__((address_space(1))) u32*)g,
      (__attribute__((address_space(3))) u32*)l, 16, 0, 0);
}
__device__ __forceinline__ void gl_lds4(const void* g, void* l) {
  __builtin_amdgcn_global_load_lds(
      (const __attribute__((address_space(1))) u32*)g,
      (__attribute__((address_space(3))) u32*)l, 4, 0, 0);
}

// ---------------------------------------------------------------------------
// prep: blocks 0..1023   pack adj -> bitmask
//       blocks 1024..1151 Xf: X (f32) -> bf16 in MFMA-A-fragment order
//       blocks 1152..1215 Bf: W (f32) -> bf16 in MFMA-B-fragment order
// Fragment layouts (16x16x32): frag(ks) = 64 lanes x 16B; lane (col,kgrp)
//   A: X[row=col][k=ks*32+kgrp*8+u]   B: W[k=ks*32+kgrp*8+u][od=nt*16+col]
// ---------------------------------------------------------------------------
__global__ __launch_bounds__(256) void prep(const float* __restrict__ X,
                                            const float* __restrict__ W,
                                            const int* __restrict__ adj,
                                            short* __restrict__ Xf,
                                            short* __restrict__ Bf,
                                            unsigned short* __restrict__ bits) {
  __shared__ float sbuf[16 * 516];  // X: [16][516]; W: [64][68]
  const int b = blockIdx.x;
  const int t = threadIdx.x;

  if (b < 1024) {  // ---- adj pack ----
    const int T = b * 256 + t;
    const int row = T >> 7, g = T & 127;
    const int* p = adj + (size_t)row * NN + g * 16;
    u32 m = 0;
#pragma unroll
    for (int q = 0; q < 4; ++q) {
      const int4 v = *(const int4*)&p[q * 4];
      m |= (v.x > 0 ? 1u : 0u) << (q * 4);
      m |= (v.y > 0 ? 2u : 0u) << (q * 4);
      m |= (v.z > 0 ? 4u : 0u) << (q * 4);
      m |= (v.w > 0 ? 8u : 0u) << (q * 4);
    }
    bits[T] = (unsigned short)m;
    return;
  }

  if (b < 1024 + 128) {  // ---- X -> Xf (m-tile = b-1024, 16 rows x 512 k) ----
    const int xb = b - 1024;
#pragma unroll
    for (int q = 0; q < 8; ++q) {
      const int flat = q * 256 + t;
      const int row = flat >> 7, c4 = flat & 127;
      const float4 v = *(const float4*)&X[(size_t)(xb * 16 + row) * KD + c4 * 4];
      *(float4*)&sbuf[row * 516 + c4 * 4] = v;
    }
    __syncthreads();
#pragma unroll
    for (int c = 0; c < 4; ++c) {
      const int s = c * 256 + t;  // slot: ks = s>>6, lane = s&63
      const int ks = s >> 6, l = s & 63;
      const int col = l & 15, kg = (l >> 4) & 3;
      const int k0 = ks * 32 + kg * 8;
      bf16x8 o;
#pragma unroll
      for (int u = 0; u < 8; ++u) o[u] = tob(sbuf[col * 516 + k0 + u]);
      *(bf16x8*)&Xf[((size_t)xb * 1024 + s) * 8] = o;
    }
    return;
  }

  // ---- W -> Bf (b2 = kb*? : kb = (b-1152)&7, h = (b-1152)>>3) ----
  const int b2 = b - 1152;
  const int kb = b2 & 7, h = b2 >> 3;
  const int k0 = kb * 64;
#pragma unroll
  for (int q = 0; q < 4; ++q) {
    const int flat = q * 256 + t;
    const int kk = flat >> 4, o4 = (flat & 15) * 4;
    const float4 v = *(const float4*)&W[(size_t)(k0 + kk) * ODIM + h * 64 + o4];
    *(float4*)&sbuf[kk * 68 + o4] = v;
  }
  __syncthreads();
#pragma unroll
  for (int c = 0; c < 2; ++c) {
    const int s = c * 256 + t;  // slot: ksl = s>>8, nt = (s>>6)&3, lane = s&63
    const int ksl = s >> 8, nt = (s >> 6) & 3, l = s & 63;
    const int col = l & 15, kg = (l >> 4) & 3;
    const int kloc = ksl * 32 + kg * 8;
    const int od = nt * 16 + col;
    bf16x8 o;
#pragma unroll
    for (int u = 0; u < 8; ++u) o[u] = tob(sbuf[(kloc + u) * 68 + od]);
    const size_t off = (((size_t)(h * 4 + nt) * 16 + kb * 2 + ksl) * 64 + l) * 8;
    *(bf16x8*)&Bf[off] = o;
  }
}

// ---------------------------------------------------------------------------
// gemm_fused: Wh = x @ W via MFMA, operands read straight from fragment-
// ordered Xf/Bf (coalesced lane*16 loads, L1/L2-hot). NO LDS, NO barriers.
// grid (32, 8), 256 thr = 4 waves; wave w: m-tile mt = bx*4+w (16 rows x 64 od).
// Epilogue: fragment-ordered WhF + exp tables (unchanged from round 7).
// ---------------------------------------------------------------------------
__global__ __launch_bounds__(256) void gemm_fused(
    const short* __restrict__ Xf, const short* __restrict__ Bf,
    const float* __restrict__ a, short* __restrict__ WhF,
    float2* __restrict__ esrcp, u32* __restrict__ edstp) {
  const int t = threadIdx.x;
  const int lane = t & 63, w = t >> 6;
  const int col = lane & 15, kgrp = lane >> 4;
  const int bm = blockIdx.x * 64;
  const int h = blockIdx.y;
  const int mt = blockIdx.x * 4 + w;

  const short* ax = Xf + (size_t)mt * 8192;
  const short* bx = Bf + (size_t)h * 32768;

  f32x4 acc[4] = {};

#pragma unroll
  for (int ks = 0; ks < 16; ++ks) {
    const bf16x8 af = *(const bf16x8*)&ax[(ks * 64 + lane) * 8];
#pragma unroll
    for (int nt = 0; nt < 4; ++nt) {
      const bf16x8 bf = *(const bf16x8*)&bx[((nt * 16 + ks) * 64 + lane) * 8];
      acc[nt] = __builtin_amdgcn_mfma_f32_16x16x32_bf16(af, bf, acc[nt], 0, 0, 0);
    }
  }

  // ---- epilogue: s-dots, exp tables, fragment-ordered Wh stores ----
  float asv[4], adv[4];
#pragma unroll
  for (int nt = 0; nt < 4; ++nt) {
    asv[nt] = a[nt * 16 + col];
    adv[nt] = a[64 + nt * 16 + col];
  }
  float ps[4], pd[4];
#pragma unroll
  for (int r = 0; r < 4; ++r) {
    float s1 = 0.f, s2 = 0.f;
#pragma unroll
    for (int nt = 0; nt < 4; ++nt) {
      s1 += acc[nt][r] * asv[nt];
      s2 += acc[nt][r] * adv[nt];
    }
    ps[r] = s1;
    pd[r] = s2;
  }
#pragma unroll
  for (int off = 1; off <= 8; off <<= 1) {
#pragma unroll
    for (int r = 0; r < 4; ++r) {
      ps[r] += __shfl_xor(ps[r], off);
      pd[r] += __shfl_xor(pd[r], off);
    }
  }
  {
    const size_t tbase = ((size_t)h * 32 + blockIdx.x) * 4096;
    const int lp = ((w & 1) * 2 + (kgrp >> 1)) * 16 + col;
    const int u0 = (kgrp & 1) * 4;
    const int slot_ks = w >> 1;
#pragma unroll
    for (int nt = 0; nt < 4; ++nt) {
      bf16x4 o;
#pragma unroll
      for (int r = 0; r < 4; ++r) o[r] = tob(acc[nt][r]);
      *(bf16x4*)&WhF[tbase + (size_t)(nt * 2 + slot_ks) * 512 + lp * 8 + u0] = o;
    }
  }
  if (col == 0) {
    const int mbase = bm + w * 16 + kgrp * 4;
#pragma unroll
    for (int r = 0; r < 4; ++r) {
      const int n = mbase + r;
      esrcp[h * NN + n] = make_float2(__expf(ps[r]), __expf(NEG * ps[r]));
      const u32 lo = (u32)(unsigned short)tob(__expf(pd[r]));
      const u32 hi = (u32)(unsigned short)tob(__expf(NEG * pd[r]));
      edstp[h * NN + n] = (hi << 16) | lo;
    }
  }
}

// ---------------------------------------------------------------------------
// attn_mfma: grid (64, 8), 256 thr = 4 waves = 4 j-quarters over 32 i-rows.
// Per-wave private LDS double-buffer; per tile 10 vm ops via global_load_lds:
// 8x B-frags (16B/lane) + 1x edstp tile (4B/lane, 256B) + 1x adj-mask tile
// (4B/lane, 256B covering rows i0..i0+31). Counted s_waitcnt vmcnt(10), no
// barriers in the main loop. p-gen reads edstp/masks from LDS (broadcast).
// ---------------------------------------------------------------------------
__global__ __launch_bounds__(256) void attn_mfma(
    const short* __restrict__ WhF, const unsigned char* __restrict__ adjbits,
    const float2* __restrict__ esrcp, const u32* __restrict__ edstp,
    float* __restrict__ out) {
  extern __shared__ __align__(16) char smem[];  // 4 waves x 2 bufs x 8704 B
  const int t = threadIdx.x;
  const int lane = t & 63;
  const int jq = t >> 6;
  const int col = lane & 15, kgrp = lane >> 4;
  const int h = blockIdx.y;
  const int i0 = blockIdx.x * 32;
  char* wbase = smem + jq * 17408;

  const short* tb = WhF + ((size_t)h * 32 + jq * 8) * 4096;
  const int jb = jq * 512;
  const int jboff = jb >> 3;

  const float2 e0 = esrcp[h * NN + i0 + col];
  const float2 e1 = esrcp[h * NN + i0 + 16 + col];
  const float A0 = e0.x, C0 = e0.y, A1 = e1.x, C1 = e1.y;

  bf16x8 ones;
#pragma unroll
  for (int u = 0; u < 8; ++u) ones[u] = (short)0x3F80;

  f32x4 acc[2][4] = {};
  f32x4 accd[2] = {};

  // ---- prologue: stage tile 0 into buf 0 ----
  {
    char* bb = wbase;
#pragma unroll
    for (int s = 0; s < 8; ++s)
      gl_lds16(tb + s * 512 + lane * 8, bb + s * 1024);
    gl_lds4(edstp + h * NN + jb + lane, bb + 8192);
    gl_lds4(adjbits + (size_t)(i0 + (lane >> 1)) * 256 + jboff + (lane & 1) * 4,
            bb + 8448);
  }

#pragma unroll
  for (int tt = 0; tt < 8; ++tt) {
    char* bcur = wbase + (tt & 1) * 8704;
    char* bnxt = wbase + ((tt + 1) & 1) * 8704;
    // ---- issue tile tt+1 (10 vm ops), then wait for tile tt ----
    if (tt < 7) {
      const short* g = tb + (size_t)(tt + 1) * 4096;
#pragma unroll
      for (int s = 0; s < 8; ++s)
        gl_lds16(g + s * 512 + lane * 8, bnxt + s * 1024);
      gl_lds4(edstp + h * NN + jb + (tt + 1) * 64 + lane, bnxt + 8192);
      gl_lds4(adjbits + (size_t)(i0 + (lane >> 1)) * 256 + jboff +
                  (tt + 1) * 8 + (lane & 1) * 4,
              bnxt + 8448);
      asm volatile("s_waitcnt vmcnt(10)" ::: "memory");
    } else {
      asm volatile("s_waitcnt vmcnt(0)" ::: "memory");
    }
    __builtin_amdgcn_sched_barrier(0);

    // ---- p-gen from LDS (broadcast reads, conflict-free) ----
    const u32* elds = (const u32*)(bcur + 8192);
    const u64 m0 = *(const u64*)(bcur + 8448 + col * 8);
    const u64 m1 = *(const u64*)(bcur + 8448 + 128 + col * 8);
    bf16x8 af0[2], af1[2];
#pragma unroll
    for (int ks = 0; ks < 2; ++ks) {
      const uint4 q0 = *(const uint4*)&elds[ks * 32 + kgrp * 8];
      const uint4 q1 = *(const uint4*)&elds[ks * 32 + kgrp * 8 + 4];
      const u32 mb0 = (u32)(m0 >> ((ks * 4 + kgrp) * 8)) & 0xffu;
      const u32 mb1 = (u32)(m1 >> ((ks * 4 + kgrp) * 8)) & 0xffu;
      const u32 uw[8] = {q0.x, q0.y, q0.z, q0.w, q1.x, q1.y, q1.z, q1.w};
#pragma unroll
      for (int u2 = 0; u2 < 8; ++u2) {
        const float B = __uint_as_float(uw[u2] << 16);
        const float D = __uint_as_float(uw[u2] & 0xffff0000u);
        float p0 = fmaxf(A0 * B, C0 * D);
        float p1 = fmaxf(A1 * B, C1 * D);
        p0 = ((mb0 >> u2) & 1u) ? p0 : 0.f;
        p1 = ((mb1 >> u2) & 1u) ? p1 : 0.f;
        af0[ks][u2] = tob(p0);
        af1[ks][u2] = tob(p1);
      }
    }

    // ---- MFMAs: denominators + 4 od-tiles ----
    const short* sb = (const short*)bcur;
    __builtin_amdgcn_s_setprio(1);
    accd[0] = __builtin_amdgcn_mfma_f32_16x16x32_bf16(af0[0], ones, accd[0], 0, 0, 0);
    accd[0] = __builtin_amdgcn_mfma_f32_16x16x32_bf16(af0[1], ones, accd[0], 0, 0, 0);
    accd[1] = __builtin_amdgcn_mfma_f32_16x16x32_bf16(af1[0], ones, accd[1], 0, 0, 0);
    accd[1] = __builtin_amdgcn_mfma_f32_16x16x32_bf16(af1[1], ones, accd[1], 0, 0, 0);
#pragma unroll
    for (int nt = 0; nt < 4; ++nt) {
      const bf16x8 b0 = *(const bf16x8*)&sb[(nt * 2 + 0) * 512 + lane * 8];
      const bf16x8 b1 = *(const bf16x8*)&sb[(nt * 2 + 1) * 512 + lane * 8];
      acc[0][nt] = __builtin_amdgcn_mfma_f32_16x16x32_bf16(af0[0], b0, acc[0][nt], 0, 0, 0);
      acc[1][nt] = __builtin_amdgcn_mfma_f32_16x16x32_bf16(af1[0], b0, acc[1][nt], 0, 0, 0);
      acc[0][nt] = __builtin_amdgcn_mfma_f32_16x16x32_bf16(af0[1], b1, acc[0][nt], 0, 0, 0);
      acc[1][nt] = __builtin_amdgcn_mfma_f32_16x16x32_bf16(af1[1], b1, acc[1][nt], 0, 0, 0);
    }
    __builtin_amdgcn_s_setprio(0);
  }

  // ---- all waves done with staging; alias reduce buffer over it ----
  __syncthreads();
  float* red = (float*)smem;  // [4 jq][32 row][66]; den at col 64
  float* rw = red + (size_t)jq * 32 * 66;
#pragma unroll
  for (int mt = 0; mt < 2; ++mt) {
#pragma unroll
    for (int nt = 0; nt < 4; ++nt)
#pragma unroll
      for (int r = 0; r < 4; ++r)
        rw[(mt * 16 + kgrp * 4 + r) * 66 + nt * 16 + col] = acc[mt][nt][r];
    if (col == 0) {
#pragma unroll
      for (int r = 0; r < 4; ++r)
        rw[(mt * 16 + kgrp * 4 + r) * 66 + 64] = accd[mt][r];
    }
  }
  __syncthreads();

  // ---- cross-jq reduce + normalize + store ----
  const int d = t & 63, rl = t >> 6;
#pragma unroll
  for (int rr = 0; rr < 8; ++rr) {
    const int row = rr * 4 + rl;
    float v = 0.f, dd = 0.f;
#pragma unroll
    for (int q = 0; q < 4; ++q) {
      v += red[((size_t)q * 32 + row) * 66 + d];
      dd += red[((size_t)q * 32 + row) * 66 + 64];
    }
    out[(size_t)(i0 + row) * ODIM + h * HD + d] = v / dd;
  }
}

// ---------------------------------------------------------------------------
extern "C" void kernel_launch(void* const* d_in, const int* in_sizes, int n_in,
                              void* d_out, int out_size, void* d_ws,
                              size_t ws_size, hipStream_t stream) {
  const float* x = (const float*)d_in[0];
  const int* adj = (const int*)d_in[1];
  const float* W = (const float*)d_in[2];
  const float* a = (const float*)d_in[3];
  float* out = (float*)d_out;

  char* ws = (char*)d_ws;
  short* WhF = (short*)ws;                                    // 2 MB
  short* Xf = (short*)(ws + (2 << 20));                       // 2 MB
  short* Bf = (short*)(ws + (4 << 20));                       // 512 KB
  unsigned short* bits =
      (unsigned short*)(ws + (4 << 20) + (512 << 10));        // 512 KB
  float2* esrcp = (float2*)(ws + (5 << 20));                  // 128 KB
  u32* edstp = (u32*)(ws + (5 << 20) + (128 << 10));          // 64 KB

  prep<<<1216, 256, 0, stream>>>(x, W, adj, Xf, Bf, bits);
  gemm_fused<<<dim3(32, 8), 256, 0, stream>>>(Xf, Bf, a, WhF, esrcp, edstp);
  attn_mfma<<<dim3(64, 8), 256, 69632, stream>>>(
      WhF, (const unsigned char*)bits, esrcp, edstp, out);
}

// Round 9
// 36.841 us; speedup vs baseline: 1.0128x; 1.0128x over previous
//
#include <hip/hip_runtime.h>
#include <hip/hip_bf16.h>

#define NN 2048
#define KD 512
#define ODIM 512
#define NHEAD 8
#define HD 64
#define NEG 0.2f

typedef float f32x4 __attribute__((ext_vector_type(4)));
typedef short bf16x8 __attribute__((ext_vector_type(8)));
typedef short bf16x4 __attribute__((ext_vector_type(4)));
typedef unsigned long long u64;
typedef unsigned int u32;

__device__ __forceinline__ short tob(float f) {
  __hip_bfloat16 h = __float2bfloat16(f);
  return *reinterpret_cast<short*>(&h);
}

// async global -> LDS; LDS dest = uniform base + lane*width
__device__ __forceinline__ void gl_lds16(const void* g, void* l) {
  __builtin_amdgcn_global_load_lds(
      (const __attribute__((address_space(1))) u32*)g,
      (__attribute__((address_space(3))) u32*)l, 16, 0, 0);
}

// LDS byte offset of a pointer (addrspace(3) cast -> 32-bit offset)
__device__ __forceinline__ u32 to_lds(const void* p) {
  return (u32)(size_t)(const __attribute__((address_space(3))) char*)p;
}

// inline-asm ds_read_b128: opaque to the waitcnt legalizer (no auto vmcnt(0));
// ordering is done manually via counted vmcnt/lgkmcnt asm + sched_barrier.
#define DSR(dst, addr, OFFLIT)                                  \
  asm volatile("ds_read_b128 %0, %1 offset:" OFFLIT             \
               : "=v"(dst)                                      \
               : "v"(addr))

// ---------------------------------------------------------------------------
// prep: blocks 0..1023   pack adj -> bitmask
//       blocks 1024..1151 Xf: X (f32) -> bf16 in MFMA-A-fragment order
//       blocks 1152..1215 Bf: W (f32) -> bf16 in MFMA-B-fragment order
// ---------------------------------------------------------------------------
__global__ __launch_bounds__(256) void prep(const float* __restrict__ X,
                                            const float* __restrict__ W,
                                            const int* __restrict__ adj,
                                            short* __restrict__ Xf,
                                            short* __restrict__ Bf,
                                            unsigned short* __restrict__ bits) {
  __shared__ float sbuf[16 * 516];
  const int b = blockIdx.x;
  const int t = threadIdx.x;

  if (b < 1024) {  // ---- adj pack ----
    const int T = b * 256 + t;
    const int row = T >> 7, g = T & 127;
    const int* p = adj + (size_t)row * NN + g * 16;
    u32 m = 0;
#pragma unroll
    for (int q = 0; q < 4; ++q) {
      const int4 v = *(const int4*)&p[q * 4];
      m |= (v.x > 0 ? 1u : 0u) << (q * 4);
      m |= (v.y > 0 ? 2u : 0u) << (q * 4);
      m |= (v.z > 0 ? 4u : 0u) << (q * 4);
      m |= (v.w > 0 ? 8u : 0u) << (q * 4);
    }
    bits[T] = (unsigned short)m;
    return;
  }

  if (b < 1024 + 128) {  // ---- X -> Xf ----
    const int xb = b - 1024;
#pragma unroll
    for (int q = 0; q < 8; ++q) {
      const int flat = q * 256 + t;
      const int row = flat >> 7, c4 = flat & 127;
      const float4 v = *(const float4*)&X[(size_t)(xb * 16 + row) * KD + c4 * 4];
      *(float4*)&sbuf[row * 516 + c4 * 4] = v;
    }
    __syncthreads();
#pragma unroll
    for (int c = 0; c < 4; ++c) {
      const int s = c * 256 + t;
      const int l = s & 63;
      const int col = l & 15, kg = (l >> 4) & 3;
      const int k0 = (s >> 6) * 32 + kg * 8;
      bf16x8 o;
#pragma unroll
      for (int u = 0; u < 8; ++u) o[u] = tob(sbuf[col * 516 + k0 + u]);
      *(bf16x8*)&Xf[((size_t)xb * 1024 + s) * 8] = o;
    }
    return;
  }

  // ---- W -> Bf ----
  const int b2 = b - 1152;
  const int kb = b2 & 7, h = b2 >> 3;
  const int k0 = kb * 64;
#pragma unroll
  for (int q = 0; q < 4; ++q) {
    const int flat = q * 256 + t;
    const int kk = flat >> 4, o4 = (flat & 15) * 4;
    const float4 v = *(const float4*)&W[(size_t)(k0 + kk) * ODIM + h * 64 + o4];
    *(float4*)&sbuf[kk * 68 + o4] = v;
  }
  __syncthreads();
#pragma unroll
  for (int c = 0; c < 2; ++c) {
    const int s = c * 256 + t;
    const int ksl = s >> 8, nt = (s >> 6) & 3, l = s & 63;
    const int col = l & 15, kg = (l >> 4) & 3;
    const int kloc = ksl * 32 + kg * 8;
    const int od = nt * 16 + col;
    bf16x8 o;
#pragma unroll
    for (int u = 0; u < 8; ++u) o[u] = tob(sbuf[(kloc + u) * 68 + od]);
    const size_t off = (((size_t)(h * 4 + nt) * 16 + kb * 2 + ksl) * 64 + l) * 8;
    *(bf16x8*)&Bf[off] = o;
  }
}

// ---------------------------------------------------------------------------
// gemm_fused: Wh = x @ W via MFMA from fragment-ordered Xf/Bf. No LDS, no
// barriers. Epilogue: fragment-ordered WhF + exp tables.
// ---------------------------------------------------------------------------
__global__ __launch_bounds__(256) void gemm_fused(
    const short* __restrict__ Xf, const short* __restrict__ Bf,
    const float* __restrict__ a, short* __restrict__ WhF,
    float2* __restrict__ esrcp, u32* __restrict__ edstp) {
  const int t = threadIdx.x;
  const int lane = t & 63, w = t >> 6;
  const int col = lane & 15, kgrp = lane >> 4;
  const int bm = blockIdx.x * 64;
  const int h = blockIdx.y;
  const int mt = blockIdx.x * 4 + w;

  const short* ax = Xf + (size_t)mt * 8192;
  const short* bx = Bf + (size_t)h * 32768;

  f32x4 acc[4] = {};

#pragma unroll
  for (int ks = 0; ks < 16; ++ks) {
    const bf16x8 af = *(const bf16x8*)&ax[(ks * 64 + lane) * 8];
#pragma unroll
    for (int nt = 0; nt < 4; ++nt) {
      const bf16x8 bf = *(const bf16x8*)&bx[((nt * 16 + ks) * 64 + lane) * 8];
      acc[nt] = __builtin_amdgcn_mfma_f32_16x16x32_bf16(af, bf, acc[nt], 0, 0, 0);
    }
  }

  float asv[4], adv[4];
#pragma unroll
  for (int nt = 0; nt < 4; ++nt) {
    asv[nt] = a[nt * 16 + col];
    adv[nt] = a[64 + nt * 16 + col];
  }
  float ps[4], pd[4];
#pragma unroll
  for (int r = 0; r < 4; ++r) {
    float s1 = 0.f, s2 = 0.f;
#pragma unroll
    for (int nt = 0; nt < 4; ++nt) {
      s1 += acc[nt][r] * asv[nt];
      s2 += acc[nt][r] * adv[nt];
    }
    ps[r] = s1;
    pd[r] = s2;
  }
#pragma unroll
  for (int off = 1; off <= 8; off <<= 1) {
#pragma unroll
    for (int r = 0; r < 4; ++r) {
      ps[r] += __shfl_xor(ps[r], off);
      pd[r] += __shfl_xor(pd[r], off);
    }
  }
  {
    const size_t tbase = ((size_t)h * 32 + blockIdx.x) * 4096;
    const int lp = ((w & 1) * 2 + (kgrp >> 1)) * 16 + col;
    const int u0 = (kgrp & 1) * 4;
    const int slot_ks = w >> 1;
#pragma unroll
    for (int nt = 0; nt < 4; ++nt) {
      bf16x4 o;
#pragma unroll
      for (int r = 0; r < 4; ++r) o[r] = tob(acc[nt][r]);
      *(bf16x4*)&WhF[tbase + (size_t)(nt * 2 + slot_ks) * 512 + lp * 8 + u0] = o;
    }
  }
  if (col == 0) {
    const int mbase = bm + w * 16 + kgrp * 4;
#pragma unroll
    for (int r = 0; r < 4; ++r) {
      const int n = mbase + r;
      esrcp[h * NN + n] = make_float2(__expf(ps[r]), __expf(NEG * ps[r]));
      const u32 lo = (u32)(unsigned short)tob(__expf(pd[r]));
      const u32 hi = (u32)(unsigned short)tob(__expf(NEG * pd[r]));
      edstp[h * NN + n] = (hi << 16) | lo;
    }
  }
}

// ---------------------------------------------------------------------------
// attn_mfma: grid (64, 8), 256 thr = 4 waves = 4 j-quarters over 32 i-rows.
// Per-wave private LDS double-buffer staged by global_load_lds (8 DMAs/tile)
// + register prefetch of edstp/adj (6 loads/tile). ALL loop LDS reads are
// inline-asm ds_read_b128, so the waitcnt legalizer cannot insert vmcnt(0)
// drains; ordering is manual: vmcnt(14) -> asm ds_reads -> p-gen ->
// lgkmcnt(0) -> sched_barrier -> MFMAs. No barriers in the main loop.
// ---------------------------------------------------------------------------
__global__ __launch_bounds__(256) void attn_mfma(
    const short* __restrict__ WhF, const unsigned char* __restrict__ adjbits,
    const float2* __restrict__ esrcp, const u32* __restrict__ edstp,
    float* __restrict__ out) {
  extern __shared__ __align__(16) char smem[];  // [4 waves][2 bufs][8192 B]
  const int t = threadIdx.x;
  const int lane = t & 63;
  const int jq = t >> 6;
  const int col = lane & 15, kgrp = lane >> 4;
  const int h = blockIdx.y;
  const int i0 = blockIdx.x * 32;
  char* wbase = smem + jq * 16384;

  const short* tb = WhF + ((size_t)h * 32 + jq * 8) * 4096;
  const int jb = jq * 512;

  const float2 e0 = esrcp[h * NN + i0 + col];
  const float2 e1 = esrcp[h * NN + i0 + 16 + col];
  const float A0 = e0.x, C0 = e0.y, A1 = e1.x, C1 = e1.y;
  const unsigned char* ab0 = adjbits + (size_t)(i0 + col) * (NN / 8);
  const unsigned char* ab1 = adjbits + (size_t)(i0 + 16 + col) * (NN / 8);

  bf16x8 ones;
#pragma unroll
  for (int u = 0; u < 8; ++u) ones[u] = (short)0x3F80;

  f32x4 acc[2][4] = {};
  f32x4 accd[2] = {};

  uint4 bd[2][4];
  u64 aw[2][2];

  // LDS read base for this wave's buffers (byte offset + lane*16)
  const u32 lbase = to_lds(wbase) + (u32)lane * 16u;

  // ---- prologue: issue tile 0 (8 DMAs + 6 register loads) ----
  {
#pragma unroll
    for (int s = 0; s < 8; ++s)
      gl_lds16(tb + s * 512 + lane * 8, wbase + s * 1024);
    const int jj0 = jb + kgrp * 8;
    bd[0][0] = *(const uint4*)&edstp[h * NN + jj0];
    bd[0][1] = *(const uint4*)&edstp[h * NN + jj0 + 4];
    bd[0][2] = *(const uint4*)&edstp[h * NN + jj0 + 32];
    bd[0][3] = *(const uint4*)&edstp[h * NN + jj0 + 36];
    aw[0][0] = *(const u64*)(ab0 + (jb >> 3));
    aw[0][1] = *(const u64*)(ab1 + (jb >> 3));
  }

#pragma unroll
  for (int tt = 0; tt < 8; ++tt) {
    const int cur = tt & 1, nxt = cur ^ 1;

    // ---- issue tile tt+1 (8 DMA + 6 reg loads = 14 vm ops), wait tile tt ----
    if (tt < 7) {
      const short* g = tb + (size_t)(tt + 1) * 4096;
      char* sb = wbase + nxt * 8192;
#pragma unroll
      for (int s = 0; s < 8; ++s)
        gl_lds16(g + s * 512 + lane * 8, sb + s * 1024);
      const int j1 = jb + (tt + 1) * 64;
      const int jj1 = j1 + kgrp * 8;
      bd[nxt][0] = *(const uint4*)&edstp[h * NN + jj1];
      bd[nxt][1] = *(const uint4*)&edstp[h * NN + jj1 + 4];
      bd[nxt][2] = *(const uint4*)&edstp[h * NN + jj1 + 32];
      bd[nxt][3] = *(const uint4*)&edstp[h * NN + jj1 + 36];
      aw[nxt][0] = *(const u64*)(ab0 + (j1 >> 3));
      aw[nxt][1] = *(const u64*)(ab1 + (j1 >> 3));
      asm volatile("s_waitcnt vmcnt(14)" ::: "memory");
    } else {
      asm volatile("s_waitcnt vmcnt(0)" ::: "memory");
    }
    __builtin_amdgcn_sched_barrier(0);

    // ---- asm ds_reads of the 8 B-fragments (LDS latency hides under p-gen)
    const u32 abuf = lbase + (u32)(cur * 8192);
    bf16x8 b0, b1, b2, b3, b4, b5, b6, b7;
    DSR(b0, abuf, "0");
    DSR(b1, abuf, "1024");
    DSR(b2, abuf, "2048");
    DSR(b3, abuf, "3072");
    DSR(b4, abuf, "4096");
    DSR(b5, abuf, "5120");
    DSR(b6, abuf, "6144");
    DSR(b7, abuf, "7168");

    // ---- p-gen (registers only, no transcendentals) ----
    bf16x8 af0[2], af1[2];
#pragma unroll
    for (int ks = 0; ks < 2; ++ks) {
      const u32 mb0 = (u32)(aw[cur][0] >> ((ks * 4 + kgrp) * 8)) & 0xffu;
      const u32 mb1 = (u32)(aw[cur][1] >> ((ks * 4 + kgrp) * 8)) & 0xffu;
      const uint4 q0 = bd[cur][ks * 2];
      const uint4 q1 = bd[cur][ks * 2 + 1];
      const u32 uw[8] = {q0.x, q0.y, q0.z, q0.w, q1.x, q1.y, q1.z, q1.w};
#pragma unroll
      for (int u2 = 0; u2 < 8; ++u2) {
        const float B = __uint_as_float(uw[u2] << 16);
        const float D = __uint_as_float(uw[u2] & 0xffff0000u);
        float p0 = fmaxf(A0 * B, C0 * D);
        float p1 = fmaxf(A1 * B, C1 * D);
        p0 = ((mb0 >> u2) & 1u) ? p0 : 0.f;
        p1 = ((mb1 >> u2) & 1u) ? p1 : 0.f;
        af0[ks][u2] = tob(p0);
        af1[ks][u2] = tob(p1);
      }
    }

    // ---- wait for ds_reads, fence scheduling (rule #18), then MFMAs ----
    asm volatile("s_waitcnt lgkmcnt(0)" ::: "memory");
    __builtin_amdgcn_sched_barrier(0);

    __builtin_amdgcn_s_setprio(1);
    accd[0] = __builtin_amdgcn_mfma_f32_16x16x32_bf16(af0[0], ones, accd[0], 0, 0, 0);
    accd[0] = __builtin_amdgcn_mfma_f32_16x16x32_bf16(af0[1], ones, accd[0], 0, 0, 0);
    accd[1] = __builtin_amdgcn_mfma_f32_16x16x32_bf16(af1[0], ones, accd[1], 0, 0, 0);
    accd[1] = __builtin_amdgcn_mfma_f32_16x16x32_bf16(af1[1], ones, accd[1], 0, 0, 0);
    acc[0][0] = __builtin_amdgcn_mfma_f32_16x16x32_bf16(af0[0], b0, acc[0][0], 0, 0, 0);
    acc[1][0] = __builtin_amdgcn_mfma_f32_16x16x32_bf16(af1[0], b0, acc[1][0], 0, 0, 0);
    acc[0][0] = __builtin_amdgcn_mfma_f32_16x16x32_bf16(af0[1], b1, acc[0][0], 0, 0, 0);
    acc[1][0] = __builtin_amdgcn_mfma_f32_16x16x32_bf16(af1[1], b1, acc[1][0], 0, 0, 0);
    acc[0][1] = __builtin_amdgcn_mfma_f32_16x16x32_bf16(af0[0], b2, acc[0][1], 0, 0, 0);
    acc[1][1] = __builtin_amdgcn_mfma_f32_16x16x32_bf16(af1[0], b2, acc[1][1], 0, 0, 0);
    acc[0][1] = __builtin_amdgcn_mfma_f32_16x16x32_bf16(af0[1], b3, acc[0][1], 0, 0, 0);
    acc[1][1] = __builtin_amdgcn_mfma_f32_16x16x32_bf16(af1[1], b3, acc[1][1], 0, 0, 0);
    acc[0][2] = __builtin_amdgcn_mfma_f32_16x16x32_bf16(af0[0], b4, acc[0][2], 0, 0, 0);
    acc[1][2] = __builtin_amdgcn_mfma_f32_16x16x32_bf16(af1[0], b4, acc[1][2], 0, 0, 0);
    acc[0][2] = __builtin_amdgcn_mfma_f32_16x16x32_bf16(af0[1], b5, acc[0][2], 0, 0, 0);
    acc[1][2] = __builtin_amdgcn_mfma_f32_16x16x32_bf16(af1[1], b5, acc[1][2], 0, 0, 0);
    acc[0][3] = __builtin_amdgcn_mfma_f32_16x16x32_bf16(af0[0], b6, acc[0][3], 0, 0, 0);
    acc[1][3] = __builtin_amdgcn_mfma_f32_16x16x32_bf16(af1[0], b6, acc[1][3], 0, 0, 0);
    acc[0][3] = __builtin_amdgcn_mfma_f32_16x16x32_bf16(af0[1], b7, acc[0][3], 0, 0, 0);
    acc[1][3] = __builtin_amdgcn_mfma_f32_16x16x32_bf16(af1[1], b7, acc[1][3], 0, 0, 0);
    __builtin_amdgcn_s_setprio(0);
  }

  // ---- all staging done; alias reduce buffer over it ----
  __syncthreads();
  float* red = (float*)smem;  // [4 jq][32 row][66]; den at col 64
  float* rw = red + (size_t)jq * 32 * 66;
#pragma unroll
  for (int mt = 0; mt < 2; ++mt) {
#pragma unroll
    for (int nt = 0; nt < 4; ++nt)
#pragma unroll
      for (int r = 0; r < 4; ++r)
        rw[(mt * 16 + kgrp * 4 + r) * 66 + nt * 16 + col] = acc[mt][nt][r];
    if (col == 0) {
#pragma unroll
      for (int r = 0; r < 4; ++r)
        rw[(mt * 16 + kgrp * 4 + r) * 66 + 64] = accd[mt][r];
    }
  }
  __syncthreads();

  // ---- cross-jq reduce + normalize + store ----
  const int d = t & 63, rl = t >> 6;
#pragma unroll
  for (int rr = 0; rr < 8; ++rr) {
    const int row = rr * 4 + rl;
    float v = 0.f, dd = 0.f;
#pragma unroll
    for (int q = 0; q < 4; ++q) {
      v += red[((size_t)q * 32 + row) * 66 + d];
      dd += red[((size_t)q * 32 + row) * 66 + 64];
    }
    out[(size_t)(i0 + row) * ODIM + h * HD + d] = v / dd;
  }
}

// ---------------------------------------------------------------------------
extern "C" void kernel_launch(void* const* d_in, const int* in_sizes, int n_in,
                              void* d_out, int out_size, void* d_ws,
                              size_t ws_size, hipStream_t stream) {
  const float* x = (const float*)d_in[0];
  const int* adj = (const int*)d_in[1];
  const float* W = (const float*)d_in[2];
  const float* a = (const float*)d_in[3];
  float* out = (float*)d_out;

  char* ws = (char*)d_ws;
  short* WhF = (short*)ws;                                    // 2 MB
  short* Xf = (short*)(ws + (2 << 20));                       // 2 MB
  short* Bf = (short*)(ws + (4 << 20));                       // 512 KB
  unsigned short* bits =
      (unsigned short*)(ws + (4 << 20) + (512 << 10));        // 512 KB
  float2* esrcp = (float2*)(ws + (5 << 20));                  // 128 KB
  u32* edstp = (u32*)(ws + (5 << 20) + (128 << 10));          // 64 KB

  prep<<<1216, 256, 0, stream>>>(x, W, adj, Xf, Bf, bits);
  gemm_fused<<<dim3(32, 8), 256, 0, stream>>>(Xf, Bf, a, WhF, esrcp, edstp);
  attn_mfma<<<dim3(64, 8), 256, 65536, stream>>>(
      WhF, (const unsigned char*)bits, esrcp, edstp, out);
}